// Round 10
// baseline (37.079 us; speedup 1.0000x reference)
//
#include <hip/hip_runtime.h>
#include <math.h>

#define NC     10
#define NCP    12     // padded row stride (floats); 48B rows, 16B aligned
#define NM     128
#define NGEN   4
#define NPT    1023
#define NTREES 1024

// d_ws float layout: bt[4][128][12] | btpi[4][128][12] | ac[4][10][12]
#define WS_BT(g)    ((g) * (NM * NCP))
#define WS_BTPI(g)  (4 * NM * NCP + (g) * (NM * NCP))
#define WS_AC(g)    (8 * NM * NCP + (g) * (NC * NCP))
#define WS_FLOATS   (8 * NM * NCP + 4 * NC * NCP)

#define RCPF(x) __builtin_amdgcn_rcpf(x)
#define WAVE_FENCE() __builtin_amdgcn_wave_barrier()

struct F12 { float4 a, b, c; };

__device__ __forceinline__ F12 ld12(const float* p) {
    F12 r; const float4* q = (const float4*)p;
    r.a = q[0]; r.b = q[1]; r.c = q[2]; return r;
}
__device__ __forceinline__ void unpack10(float* t, const F12& r) {
    t[0] = r.a.x; t[1] = r.a.y; t[2] = r.a.z; t[3] = r.a.w;
    t[4] = r.b.x; t[5] = r.b.y; t[6] = r.b.z; t[7] = r.b.w;
    t[8] = r.c.x; t[9] = r.c.y;
}
__device__ __forceinline__ void fma10(float* t, const F12& c, float s) {
    t[0] += c.a.x * s; t[1] += c.a.y * s; t[2] += c.a.z * s; t[3] += c.a.w * s;
    t[4] += c.b.x * s; t[5] += c.b.y * s; t[6] += c.b.z * s; t[7] += c.b.w * s;
    t[8] += c.c.x * s; t[9] += c.c.y * s;
}
__device__ __forceinline__ void mul10(float* t, const F12& r) {
    t[0] *= r.a.x; t[1] *= r.a.y; t[2] *= r.a.z; t[3] *= r.a.w;
    t[4] *= r.b.x; t[5] *= r.b.y; t[6] *= r.b.z; t[7] *= r.b.w;
    t[8] *= r.c.x; t[9] *= r.c.y;
}
__device__ __forceinline__ float sum10(const float* v) {
    return (((v[0] + v[1]) + (v[2] + v[3])) + ((v[4] + v[5]) + (v[6] + v[7]))) + (v[8] + v[9]);
}

// two leaves from the global pi*B table -> normalized pair-sum sc
__device__ __forceinline__ float leaf_pair(const float* btpi, int xv0, int xv1, float* sc) {
    float b0[NC], b1[NC];
    unpack10(b0, ld12(btpi + NCP * xv0));
    unpack10(b1, ld12(btpi + NCP * xv1));
    const float nu0 = sum10(b0), nu1 = sum10(b1);
    const float r0 = RCPF(nu0), r1 = RCPF(nu1);
    #pragma unroll
    for (int j = 0; j < NC; ++j) sc[j] = b0[j] * r0 + b1[j] * r1;
    return __logf(nu0) + __logf(nu1);
}

// one internal node (A in registers, B row from global/L1)
__device__ __forceinline__ float node_step(const F12* acol, const float* bt,
                                           const float* sc, int xv, float* bout) {
    float t[NC];
    #pragma unroll
    for (int i = 0; i < NC; ++i) t[i] = 0.f;
    #pragma unroll
    for (int j = 0; j < NC; ++j) fma10(t, acol[j], sc[j]);
    mul10(t, ld12(bt + NCP * xv));
    const float nu = sum10(t);
    const float r = RCPF(nu);
    #pragma unroll
    for (int j = 0; j < NC; ++j) bout[j] = t[j] * r;
    return __logf(nu);
}

// fused 2-level step, SoA LDS buffer in place (stride 64), B rows from global.
// All reads precede the write in program order; DS ops in-order per wave
// (in-place tail verified correct in R7/R8/R9).
__device__ __forceinline__ float fused_step_ip(const F12* acol, const float* bt,
                                               float* buf, int l,
                                               int xc0, int xc1, int xp)
{
    float t0[NC], t1[NC];
    #pragma unroll
    for (int i = 0; i < NC; ++i) { t0[i] = 0.f; t1[i] = 0.f; }
    #pragma unroll
    for (int j = 0; j < NC; ++j) {
        float4 gv = *(const float4*)(buf + j * 64 + 4 * l);
        fma10(t0, acol[j], gv.x + gv.y);
        fma10(t1, acol[j], gv.z + gv.w);
    }
    mul10(t0, ld12(bt + NCP * xc0));
    mul10(t1, ld12(bt + NCP * xc1));
    const float nu0 = sum10(t0), nu1 = sum10(t1);
    const float r0 = RCPF(nu0), r1 = RCPF(nu1);
    float ll = __logf(nu0) + __logf(nu1);

    float tp[NC];
    #pragma unroll
    for (int i = 0; i < NC; ++i) tp[i] = 0.f;
    #pragma unroll
    for (int j = 0; j < NC; ++j)
        fma10(tp, acol[j], t0[j] * r0 + t1[j] * r1);
    mul10(tp, ld12(bt + NCP * xp));
    const float nup = sum10(tp);
    ll += __logf(nup);
    const float rp = RCPF(nup);
    #pragma unroll
    for (int j = 0; j < NC; ++j) buf[j * 64 + l] = tp[j] * rp;
    return ll;
}

// ---------------- kernel 0: softmax all parameter tables into d_ws ----------------
// 4 blocks (one per g) x 256 threads. Runs once per launch; ~µs.
__global__ __launch_bounds__(256)
void htmm_setup(const float* __restrict__ A,
                const float* __restrict__ B,
                const float* __restrict__ Pi,
                float* __restrict__ ws)
{
    __shared__ float sPi[NCP];
    const int g = blockIdx.x;
    const int tid = threadIdx.x;
    const int wave = tid >> 6, lane = tid & 63;
    float* bt   = ws + WS_BT(g);
    float* btpi = ws + WS_BTPI(g);
    float* ac   = ws + WS_AC(g);

    if (tid == 16) {   // Pi softmax
        float col[NC], mx = -1e30f;
        #pragma unroll
        for (int i = 0; i < NC; ++i) { col[i] = Pi[i * NGEN + g]; mx = fmaxf(mx, col[i]); }
        float s = 0.f;
        #pragma unroll
        for (int i = 0; i < NC; ++i) { col[i] = __expf(col[i] - mx); s += col[i]; }
        const float rs = 1.f / s;
        #pragma unroll
        for (int i = 0; i < NC; ++i) sPi[i] = col[i] * rs;
    }
    if (tid < NC) {    // A column softmax, 0.5 folded, col-major rows of 12
        const int j = tid;
        float col[NC], mx = -1e30f;
        #pragma unroll
        for (int i = 0; i < NC; ++i) { col[i] = A[(i * NC + j) * NGEN + g]; mx = fmaxf(mx, col[i]); }
        float s = 0.f;
        #pragma unroll
        for (int i = 0; i < NC; ++i) { col[i] = __expf(col[i] - mx); s += col[i]; }
        const float rs = 0.5f / s;
        #pragma unroll
        for (int i = 0; i < NC; ++i) ac[j * NCP + i] = col[i] * rs;
        ac[j * NCP + 10] = 0.f; ac[j * NCP + 11] = 0.f;
    }
    __syncthreads();

    // B row softmax (axis=1 over M), wave-parallel; write bt and pi-folded btpi
    for (int c = wave; c < NC; c += 4) {
        float v0 = B[(c * NM + lane) * NGEN + g];
        float v1 = B[(c * NM + lane + 64) * NGEN + g];
        float mx = fmaxf(v0, v1);
        #pragma unroll
        for (int off = 32; off; off >>= 1) mx = fmaxf(mx, __shfl_xor(mx, off));
        float e0 = __expf(v0 - mx), e1 = __expf(v1 - mx);
        float s = e0 + e1;
        #pragma unroll
        for (int off = 32; off; off >>= 1) s += __shfl_xor(s, off);
        const float rs = 1.f / s;
        const float pic = sPi[c];
        bt[lane * NCP + c]          = e0 * rs;
        bt[(lane + 64) * NCP + c]   = e1 * rs;
        btpi[lane * NCP + c]        = e0 * rs * pic;
        btpi[(lane + 64) * NCP + c] = e1 * rs * pic;
    }
    if (tid < NM) {    // zero the row pads (they are loaded by ld12, never used)
        bt[tid * NCP + 10] = 0.f;   bt[tid * NCP + 11] = 0.f;
        btpi[tid * NCP + 10] = 0.f; btpi[tid * NCP + 11] = 0.f;
    }
}

// ---------------- kernel 1: one wave per (tree,g) unit ----------------
// Lane = one L6 subtree (8 leaves + 4 L8 + 2 L7 + 1 L6) sequentially in
// registers; A in 30 VGPRs; B-row gathers via global_load_dwordx4 (L1-resident
// 20KB tables) — off the LDS pipe. No __syncthreads anywhere. Tail in place.
__global__ __launch_bounds__(64)
void htmm_main(const int* __restrict__ x,
               const float* __restrict__ ws,
               float* __restrict__ out)
{
    __shared__ __align__(16) float sB6[NC][64];

    const int bid  = blockIdx.x;
    const int tree = bid >> 2;
    const int g    = bid & 3;
    const int lane = threadIdx.x;

    const float* bt   = ws + WS_BT(g);
    const float* btpi = ws + WS_BTPI(g);
    const float* ac   = ws + WS_AC(g);

    // A columns into registers (wave-uniform loads, L1/L2-cached)
    F12 acol[NC];
    #pragma unroll
    for (int j = 0; j < NC; ++j) acol[j] = ld12(ac + j * NCP);

    const int tb = tree * NPT;
    const int s = lane;

    // observation indices for this lane's subtree
    int xl[8];
    #pragma unroll
    for (int k = 0; k < 8; ++k) xl[k] = x[tb + 511 + 8 * s + k];
    int x8v[4];
    #pragma unroll
    for (int c = 0; c < 4; ++c) x8v[c] = x[tb + 255 + 4 * s + c];
    const int x7a = x[tb + 127 + 2 * s];
    const int x7b = x[tb + 128 + 2 * s];
    const int x6v = x[tb + 63 + s];

    float llacc = 0.f;
    float sc[NC], ba[NC], bb[NC], b7a[NC], b7b[NC];

    // left half: leaves 0-3 -> L8 nodes 0,1 -> L7 node a
    llacc += leaf_pair(btpi, xl[0], xl[1], sc);
    llacc += node_step(acol, bt, sc, x8v[0], ba);
    llacc += leaf_pair(btpi, xl[2], xl[3], sc);
    llacc += node_step(acol, bt, sc, x8v[1], bb);
    #pragma unroll
    for (int j = 0; j < NC; ++j) sc[j] = ba[j] + bb[j];
    llacc += node_step(acol, bt, sc, x7a, b7a);

    // right half: leaves 4-7 -> L8 nodes 2,3 -> L7 node b
    llacc += leaf_pair(btpi, xl[4], xl[5], sc);
    llacc += node_step(acol, bt, sc, x8v[2], ba);
    llacc += leaf_pair(btpi, xl[6], xl[7], sc);
    llacc += node_step(acol, bt, sc, x8v[3], bb);
    #pragma unroll
    for (int j = 0; j < NC; ++j) sc[j] = ba[j] + bb[j];
    llacc += node_step(acol, bt, sc, x7b, b7b);

    // L6 node
    #pragma unroll
    for (int j = 0; j < NC; ++j) sc[j] = b7a[j] + b7b[j];
    llacc += node_step(acol, bt, sc, x6v, ba);
    #pragma unroll
    for (int j = 0; j < NC; ++j) sB6[j][s] = ba[j];   // SoA, lane-contiguous

    // ---- tail: levels 5..0, wave-local, in place in sB6 ----
    WAVE_FENCE();
    float lla = 0.f;
    if (lane < 16)
        lla = fused_step_ip(acol, bt, &sB6[0][0], lane,
                            x[tb + 31 + 2 * lane], x[tb + 32 + 2 * lane],
                            x[tb + 15 + lane]);
    llacc += lla;
    WAVE_FENCE();
    float llb = 0.f;
    if (lane < 4)
        llb = fused_step_ip(acol, bt, &sB6[0][0], lane,
                            x[tb + 7 + 2 * lane], x[tb + 8 + 2 * lane],
                            x[tb + 3 + lane]);
    llacc += llb;
    WAVE_FENCE();
    if (lane == 0)
        llacc += fused_step_ip(acol, bt, &sB6[0][0], 0,
                               x[tb + 1], x[tb + 2], x[tb + 0]);

    // ---- full-wave reduce; lane 0 writes the unit's output ----
    #pragma unroll
    for (int off = 32; off; off >>= 1) llacc += __shfl_down(llacc, off);
    if (lane == 0) out[tree * NGEN + g] = llacc;
}

// ---------------- fallback: R9 monolithic kernel (known-good, 28.5 µs) ----------------
__global__ __launch_bounds__(256)
void htmm_fused(const int* __restrict__ x,
                const float* __restrict__ A,
                const float* __restrict__ B,
                const float* __restrict__ Pi,
                float* __restrict__ out)
{
    __shared__ __align__(16) float sACol[NC][NCP];
    __shared__ __align__(16) float sBT[NM][NCP];
    __shared__ __align__(16) float sBTpi[NM][NCP];
    __shared__ __align__(16) float sPiP[NCP];
    __shared__ __align__(16) float sB6[4][NC][64];

    const int bid = blockIdx.x;
    const int g = bid >> 8;
    const int treeBase = (bid & 255) * 4;
    const int tid = threadIdx.x;
    const int u = tid >> 6, lane = tid & 63;

    {
        for (int c = u; c < NC; c += 4) {
            float v0 = B[(c * NM + lane) * NGEN + g];
            float v1 = B[(c * NM + lane + 64) * NGEN + g];
            float mx = fmaxf(v0, v1);
            #pragma unroll
            for (int off = 32; off; off >>= 1) mx = fmaxf(mx, __shfl_xor(mx, off));
            float e0 = __expf(v0 - mx), e1 = __expf(v1 - mx);
            float s = e0 + e1;
            #pragma unroll
            for (int off = 32; off; off >>= 1) s += __shfl_xor(s, off);
            float rs = 1.f / s;
            sBT[lane][c]      = e0 * rs;
            sBT[lane + 64][c] = e1 * rs;
        }
        if (tid < NC) {
            const int j = tid;
            float col[NC], mx = -1e30f;
            #pragma unroll
            for (int i = 0; i < NC; ++i) { col[i] = A[(i * NC + j) * NGEN + g]; mx = fmaxf(mx, col[i]); }
            float s = 0.f;
            #pragma unroll
            for (int i = 0; i < NC; ++i) { col[i] = __expf(col[i] - mx); s += col[i]; }
            const float rs = 0.5f / s;
            #pragma unroll
            for (int i = 0; i < NC; ++i) sACol[j][i] = col[i] * rs;
            sACol[j][10] = 0.f; sACol[j][11] = 0.f;
        }
        if (tid == 16) {
            float col[NC], mx = -1e30f;
            #pragma unroll
            for (int i = 0; i < NC; ++i) { col[i] = Pi[i * NGEN + g]; mx = fmaxf(mx, col[i]); }
            float s = 0.f;
            #pragma unroll
            for (int i = 0; i < NC; ++i) { col[i] = __expf(col[i] - mx); s += col[i]; }
            const float rs = 1.f / s;
            #pragma unroll
            for (int i = 0; i < NC; ++i) sPiP[i] = col[i] * rs;
            sPiP[10] = 0.f; sPiP[11] = 0.f;
        }
    }
    __syncthreads();
    if (tid < NM) {
        F12 pi = ld12(sPiP);
        F12 r  = ld12(&sBT[tid][0]);
        sBTpi[tid][0] = pi.a.x * r.a.x; sBTpi[tid][1] = pi.a.y * r.a.y;
        sBTpi[tid][2] = pi.a.z * r.a.z; sBTpi[tid][3] = pi.a.w * r.a.w;
        sBTpi[tid][4] = pi.b.x * r.b.x; sBTpi[tid][5] = pi.b.y * r.b.y;
        sBTpi[tid][6] = pi.b.z * r.b.z; sBTpi[tid][7] = pi.b.w * r.b.w;
        sBTpi[tid][8] = pi.c.x * r.c.x; sBTpi[tid][9] = pi.c.y * r.c.y;
    }
    __syncthreads();

    F12 acol[NC];
    #pragma unroll
    for (int j = 0; j < NC; ++j) acol[j] = ld12(&sACol[j][0]);

    const int tree = treeBase + u;
    const int tb = tree * NPT;
    const int s = lane;

    int xl[8];
    #pragma unroll
    for (int k = 0; k < 8; ++k) xl[k] = x[tb + 511 + 8 * s + k];
    int x8v[4];
    #pragma unroll
    for (int c = 0; c < 4; ++c) x8v[c] = x[tb + 255 + 4 * s + c];
    const int x7a = x[tb + 127 + 2 * s];
    const int x7b = x[tb + 128 + 2 * s];
    const int x6v = x[tb + 63 + s];

    float llacc = 0.f;
    float sc[NC], ba[NC], bb[NC], b7a[NC], b7b[NC];

    llacc += leaf_pair(&sBTpi[0][0], xl[0], xl[1], sc);
    llacc += node_step(acol, &sBT[0][0], sc, x8v[0], ba);
    llacc += leaf_pair(&sBTpi[0][0], xl[2], xl[3], sc);
    llacc += node_step(acol, &sBT[0][0], sc, x8v[1], bb);
    #pragma unroll
    for (int j = 0; j < NC; ++j) sc[j] = ba[j] + bb[j];
    llacc += node_step(acol, &sBT[0][0], sc, x7a, b7a);

    llacc += leaf_pair(&sBTpi[0][0], xl[4], xl[5], sc);
    llacc += node_step(acol, &sBT[0][0], sc, x8v[2], ba);
    llacc += leaf_pair(&sBTpi[0][0], xl[6], xl[7], sc);
    llacc += node_step(acol, &sBT[0][0], sc, x8v[3], bb);
    #pragma unroll
    for (int j = 0; j < NC; ++j) sc[j] = ba[j] + bb[j];
    llacc += node_step(acol, &sBT[0][0], sc, x7b, b7b);

    #pragma unroll
    for (int j = 0; j < NC; ++j) sc[j] = b7a[j] + b7b[j];
    llacc += node_step(acol, &sBT[0][0], sc, x6v, ba);
    #pragma unroll
    for (int j = 0; j < NC; ++j) sB6[u][j][s] = ba[j];

    WAVE_FENCE();
    float lla = 0.f;
    if (lane < 16)
        lla = fused_step_ip(acol, &sBT[0][0], &sB6[u][0][0], lane,
                            x[tb + 31 + 2 * lane], x[tb + 32 + 2 * lane],
                            x[tb + 15 + lane]);
    llacc += lla;
    WAVE_FENCE();
    float llb = 0.f;
    if (lane < 4)
        llb = fused_step_ip(acol, &sBT[0][0], &sB6[u][0][0], lane,
                            x[tb + 7 + 2 * lane], x[tb + 8 + 2 * lane],
                            x[tb + 3 + lane]);
    llacc += llb;
    WAVE_FENCE();
    if (lane == 0)
        llacc += fused_step_ip(acol, &sBT[0][0], &sB6[u][0][0], 0,
                               x[tb + 1], x[tb + 2], x[tb + 0]);

    #pragma unroll
    for (int off = 32; off; off >>= 1) llacc += __shfl_down(llacc, off);
    if (lane == 0) out[tree * NGEN + g] = llacc;
}

extern "C" void kernel_launch(void* const* d_in, const int* in_sizes, int n_in,
                              void* d_out, int out_size, void* d_ws, size_t ws_size,
                              hipStream_t stream) {
    const int*   x  = (const int*)d_in[0];
    const float* A  = (const float*)d_in[1];
    const float* B  = (const float*)d_in[2];
    const float* Pi = (const float*)d_in[3];
    float* out = (float*)d_out;

    if (ws_size >= (size_t)WS_FLOATS * sizeof(float)) {
        float* ws = (float*)d_ws;
        htmm_setup<<<NGEN, 256, 0, stream>>>(A, B, Pi, ws);
        htmm_main<<<NTREES * NGEN, 64, 0, stream>>>(x, ws, out);
    } else {
        htmm_fused<<<NTREES, 256, 0, stream>>>(x, A, B, Pi, out);
    }
}

// Round 11
// 26.061 us; speedup vs baseline: 1.4228x; 1.4228x over previous
//
#include <hip/hip_runtime.h>
#include <math.h>

#define NC     10
#define NCP    12     // padded row stride (floats); 48B rows, 16B aligned
#define NM     128
#define NGEN   4
#define NPT    1023
#define NTREES 1024

#define RCPF(x) __builtin_amdgcn_rcpf(x)
#define WAVE_FENCE() __builtin_amdgcn_wave_barrier()

struct F12 { float4 a, b, c; };

__device__ __forceinline__ F12 ld12(const float* p) {
    F12 r; const float4* q = (const float4*)p;
    r.a = q[0]; r.b = q[1]; r.c = q[2]; return r;
}
__device__ __forceinline__ void unpack10(float* t, const F12& r) {
    t[0] = r.a.x; t[1] = r.a.y; t[2] = r.a.z; t[3] = r.a.w;
    t[4] = r.b.x; t[5] = r.b.y; t[6] = r.b.z; t[7] = r.b.w;
    t[8] = r.c.x; t[9] = r.c.y;
}
__device__ __forceinline__ void fma10(float* t, const F12& c, float s) {
    t[0] += c.a.x * s; t[1] += c.a.y * s; t[2] += c.a.z * s; t[3] += c.a.w * s;
    t[4] += c.b.x * s; t[5] += c.b.y * s; t[6] += c.b.z * s; t[7] += c.b.w * s;
    t[8] += c.c.x * s; t[9] += c.c.y * s;
}
__device__ __forceinline__ void mul10(float* t, const F12& r) {
    t[0] *= r.a.x; t[1] *= r.a.y; t[2] *= r.a.z; t[3] *= r.a.w;
    t[4] *= r.b.x; t[5] *= r.b.y; t[6] *= r.b.z; t[7] *= r.b.w;
    t[8] *= r.c.x; t[9] *= r.c.y;
}
__device__ __forceinline__ float sum10(const float* v) {
    return (((v[0] + v[1]) + (v[2] + v[3])) + ((v[4] + v[5]) + (v[6] + v[7]))) + (v[8] + v[9]);
}

// ---- telescoped 3-node groups -------------------------------------------
// {leaf0, leaf1, parent}: sc' = b0*nu1 + b1*nu0 (scale nu0*nu1); parent
// nu' = nu_p*nu0*nu1 so ONE log covers all three nodes; ONE rcp normalizes
// the parent EXACTLY (beta_p = t/nu' is scale-free). Algebra is exact.
__device__ __forceinline__ float group3_leaf(const F12* acol, const float (*bt)[NCP],
                                             const float (*btpi)[NCP],
                                             int xl0, int xl1, int xp, float* bout) {
    float b0[NC], b1[NC];
    unpack10(b0, ld12(&btpi[xl0][0]));
    unpack10(b1, ld12(&btpi[xl1][0]));
    const float nu0 = sum10(b0), nu1 = sum10(b1);
    float t[NC];
    #pragma unroll
    for (int i = 0; i < NC; ++i) t[i] = 0.f;
    #pragma unroll
    for (int j = 0; j < NC; ++j) fma10(t, acol[j], b0[j] * nu1 + b1[j] * nu0);
    mul10(t, ld12(&bt[xp][0]));
    const float nup = sum10(t);
    const float r = RCPF(nup);
    #pragma unroll
    for (int j = 0; j < NC; ++j) bout[j] = t[j] * r;
    return __logf(nup);
}

// unnormalized node from two normalized children: uo = (A*(c0+c1)) .* Brow
__device__ __forceinline__ float node_unnorm(const F12* acol, const float (*bt)[NCP],
                                             const float* c0, const float* c1,
                                             int xv, float* uo) {
    float t[NC];
    #pragma unroll
    for (int i = 0; i < NC; ++i) t[i] = 0.f;
    #pragma unroll
    for (int j = 0; j < NC; ++j) fma10(t, acol[j], c0[j] + c1[j]);
    mul10(t, ld12(&bt[xv][0]));
    #pragma unroll
    for (int j = 0; j < NC; ++j) uo[j] = t[j];
    return sum10(t);
}

// {unnorm u0, unnorm u1, parent}: one log covers u0,u1,parent; one rcp.
__device__ __forceinline__ float group3_mid(const F12* acol, const float (*bt)[NCP],
                                            const float* u0, float nu0,
                                            const float* u1, float nu1,
                                            int xp, float* bout) {
    float t[NC];
    #pragma unroll
    for (int i = 0; i < NC; ++i) t[i] = 0.f;
    #pragma unroll
    for (int j = 0; j < NC; ++j) fma10(t, acol[j], u0[j] * nu1 + u1[j] * nu0);
    mul10(t, ld12(&bt[xp][0]));
    const float nup = sum10(t);
    const float r = RCPF(nup);
    #pragma unroll
    for (int j = 0; j < NC; ++j) bout[j] = t[j] * r;
    return __logf(nup);
}

// fused 2-level tail step, in place (stride 64), telescoped (1 log, 1 rcp).
__device__ __forceinline__ float fused_step_ip(const F12* acol, const float (*bt)[NCP],
                                               float* buf, int l,
                                               int xc0, int xc1, int xp)
{
    float t0[NC], t1[NC];
    #pragma unroll
    for (int i = 0; i < NC; ++i) { t0[i] = 0.f; t1[i] = 0.f; }
    #pragma unroll
    for (int j = 0; j < NC; ++j) {
        float4 gv = *(const float4*)(buf + j * 64 + 4 * l);
        fma10(t0, acol[j], gv.x + gv.y);
        fma10(t1, acol[j], gv.z + gv.w);
    }
    mul10(t0, ld12(&bt[xc0][0]));
    mul10(t1, ld12(&bt[xc1][0]));
    const float nu0 = sum10(t0), nu1 = sum10(t1);
    float tp[NC];
    #pragma unroll
    for (int i = 0; i < NC; ++i) tp[i] = 0.f;
    #pragma unroll
    for (int j = 0; j < NC; ++j) fma10(tp, acol[j], t0[j] * nu1 + t1[j] * nu0);
    mul10(tp, ld12(&bt[xp][0]));
    const float nup = sum10(tp);
    const float rp = RCPF(nup);
    #pragma unroll
    for (int j = 0; j < NC; ++j) buf[j * 64 + l] = tp[j] * rp;
    return __logf(nup);   // = log nu_p + log nu0 + log nu1 exactly
}

// ---------------- single fused kernel ----------------
// block = 256 threads = 4 (tree,g) units (one wave each, same g per block).
// Lane = one L6 subtree in registers; A in 30 VGPRs; telescoped norm:
// 5 rcp+log per lane head (was 15). x loads hoisted above setup.
// NO launch_bounds min-waves (R7: caps VGPR -> 600MB scratch spill).
__global__ __launch_bounds__(256)
void htmm_fused(const int* __restrict__ x,
                const float* __restrict__ A,
                const float* __restrict__ B,
                const float* __restrict__ Pi,
                float* __restrict__ out)
{
    __shared__ __align__(16) float sACol[NC][NCP];   // 0.5*smA[i][j], col-major
    __shared__ __align__(16) float sBT[NM][NCP];     // smB^T rows
    __shared__ __align__(16) float sBTpi[NM][NCP];   // pi (.) smB^T rows (leaves)
    __shared__ __align__(16) float sPiP[NCP];
    __shared__ __align__(16) float sB6[4][NC][64];   // per-unit SoA; tail in place

    const int bid = blockIdx.x;
    const int g = bid >> 8;
    const int treeBase = (bid & 255) * 4;
    const int tid = threadIdx.x;
    const int u = tid >> 6, lane = tid & 63;

    const int tree = treeBase + u;
    const int tb = tree * NPT;

    // ---- hoisted observation-index loads (overlap setup latency) ----
    int xl[8];
    #pragma unroll
    for (int k = 0; k < 8; ++k) xl[k] = x[tb + 511 + 8 * lane + k];
    int x8v[4];
    #pragma unroll
    for (int c = 0; c < 4; ++c) x8v[c] = x[tb + 255 + 4 * lane + c];
    const int x7a = x[tb + 127 + 2 * lane];
    const int x7b = x[tb + 128 + 2 * lane];
    const int x6v = x[tb + 63 + lane];

    // ---- parameter softmaxes (B: no-max — |2.5*N| <= ~12, exp safe) ----
    for (int c = u; c < NC; c += 4) {
        float e0 = __expf(B[(c * NM + lane) * NGEN + g]);
        float e1 = __expf(B[(c * NM + lane + 64) * NGEN + g]);
        float sm = e0 + e1;
        #pragma unroll
        for (int off = 32; off; off >>= 1) sm += __shfl_xor(sm, off);
        const float rs = 1.f / sm;
        sBT[lane][c]      = e0 * rs;
        sBT[lane + 64][c] = e1 * rs;
    }
    if (tid >= 128 && tid < 128 + NC) {   // A column softmax on wave 2 (2 B-rows)
        const int j = tid - 128;
        float col[NC], mx = -1e30f;
        #pragma unroll
        for (int i = 0; i < NC; ++i) { col[i] = A[(i * NC + j) * NGEN + g]; mx = fmaxf(mx, col[i]); }
        float sm = 0.f;
        #pragma unroll
        for (int i = 0; i < NC; ++i) { col[i] = __expf(col[i] - mx); sm += col[i]; }
        const float rs = 0.5f / sm;
        #pragma unroll
        for (int i = 0; i < NC; ++i) sACol[j][i] = col[i] * rs;
    }
    if (tid == 192) {                     // Pi softmax on wave 3
        float col[NC], mx = -1e30f;
        #pragma unroll
        for (int i = 0; i < NC; ++i) { col[i] = Pi[i * NGEN + g]; mx = fmaxf(mx, col[i]); }
        float sm = 0.f;
        #pragma unroll
        for (int i = 0; i < NC; ++i) { col[i] = __expf(col[i] - mx); sm += col[i]; }
        const float rs = 1.f / sm;
        #pragma unroll
        for (int i = 0; i < NC; ++i) sPiP[i] = col[i] * rs;
    }
    __syncthreads();
    if (tid < NM) {   // sBTpi[m][c] = pi[c] * sBT[m][c]
        F12 pi = ld12(sPiP);
        F12 r  = ld12(&sBT[tid][0]);
        sBTpi[tid][0] = pi.a.x * r.a.x; sBTpi[tid][1] = pi.a.y * r.a.y;
        sBTpi[tid][2] = pi.a.z * r.a.z; sBTpi[tid][3] = pi.a.w * r.a.w;
        sBTpi[tid][4] = pi.b.x * r.b.x; sBTpi[tid][5] = pi.b.y * r.b.y;
        sBTpi[tid][6] = pi.b.z * r.b.z; sBTpi[tid][7] = pi.b.w * r.b.w;
        sBTpi[tid][8] = pi.c.x * r.c.x; sBTpi[tid][9] = pi.c.y * r.c.y;
    }
    __syncthreads();

    // ---- hoist A into registers (one-time broadcast reads) ----
    F12 acol[NC];
    #pragma unroll
    for (int j = 0; j < NC; ++j) acol[j] = ld12(&sACol[j][0]);

    float llacc;
    float ba[NC], bb[NC], u7a[NC], u7b[NC];

    // left half: two leaf-groups -> unnormalized L7a
    llacc  = group3_leaf(acol, sBT, sBTpi, xl[0], xl[1], x8v[0], ba);
    llacc += group3_leaf(acol, sBT, sBTpi, xl[2], xl[3], x8v[1], bb);
    const float nu7a = node_unnorm(acol, sBT, ba, bb, x7a, u7a);

    // right half
    llacc += group3_leaf(acol, sBT, sBTpi, xl[4], xl[5], x8v[2], ba);
    llacc += group3_leaf(acol, sBT, sBTpi, xl[6], xl[7], x8v[3], bb);
    const float nu7b = node_unnorm(acol, sBT, ba, bb, x7b, u7b);

    // {L7a, L7b, L6} telescoped group -> normalized L6 beta
    llacc += group3_mid(acol, sBT, u7a, nu7a, u7b, nu7b, x6v, ba);
    #pragma unroll
    for (int j = 0; j < NC; ++j) sB6[u][j][lane] = ba[j];   // SoA, lane-contiguous

    // ---- tail: levels 5..0, wave-local, in place in sB6 ----
    WAVE_FENCE();
    float lla = 0.f;
    if (lane < 16)
        lla = fused_step_ip(acol, sBT, &sB6[u][0][0], lane,
                            x[tb + 31 + 2 * lane], x[tb + 32 + 2 * lane],
                            x[tb + 15 + lane]);
    llacc += lla;
    WAVE_FENCE();
    float llb = 0.f;
    if (lane < 4)
        llb = fused_step_ip(acol, sBT, &sB6[u][0][0], lane,
                            x[tb + 7 + 2 * lane], x[tb + 8 + 2 * lane],
                            x[tb + 3 + lane]);
    llacc += llb;
    WAVE_FENCE();
    if (lane == 0)
        llacc += fused_step_ip(acol, sBT, &sB6[u][0][0], 0,
                               x[tb + 1], x[tb + 2], x[tb + 0]);

    // ---- full-wave reduce; lane 0 writes the unit's output ----
    #pragma unroll
    for (int off = 32; off; off >>= 1) llacc += __shfl_down(llacc, off);
    if (lane == 0) out[tree * NGEN + g] = llacc;
}

extern "C" void kernel_launch(void* const* d_in, const int* in_sizes, int n_in,
                              void* d_out, int out_size, void* d_ws, size_t ws_size,
                              hipStream_t stream) {
    const int*   x  = (const int*)d_in[0];
    const float* A  = (const float*)d_in[1];
    const float* B  = (const float*)d_in[2];
    const float* Pi = (const float*)d_in[3];
    float* out = (float*)d_out;
    htmm_fused<<<NTREES, 256, 0, stream>>>(x, A, B, Pi, out);
}